// Round 8
// baseline (153.780 us; speedup 1.0000x reference)
//
#include <hip/hip_runtime.h>
#include <cstdint>
#include <cstddef>

#define N_ROWS 3456   // 16*216 chunks
#define C_DIM 256
#define K_CB 1024
#define B_SZ 16
#define SPATIAL 216
#define VOX 13824     // 24*24*24
#define NCH 32
#define N_GBLK 108    // fused gemm+stat blocks (32 rows x 1024 cols each)
#define N_FBLK 486    // 108 gemm + 378 ham

typedef __attribute__((ext_vector_type(16))) float f32x16;
typedef __attribute__((ext_vector_type(8))) short bf16x8;

__device__ __forceinline__ unsigned short f2bf_rne(float f) {
    unsigned int u = __float_as_uint(f);
    u += 0x7FFFu + ((u >> 16) & 1u);
    return (unsigned short)(u >> 16);
}
__device__ __forceinline__ float bf2f(unsigned short h) {
    unsigned int u = ((unsigned int)h) << 16;
    return __uint_as_float(u);
}

// Swizzled fragment layout: element (row n, col c) of a [rows x 256] matrix
// lives at  strip(n>>5)*8192 + (c>>3)*256 + (n&31)*8 + (c&7).
__device__ __forceinline__ size_t swz(int n, int c) {
    return (size_t)(n >> 5) * 8192 + (size_t)((c >> 3) * 256) + (size_t)((n & 31) * 8) + (c & 7);
}

// ---------------- K1: fused preprocessing: patterns + init + cb/z norm+split
// grid: [0,432) patterns (2 voxels/thread, float2) ; [432,1456) codebook ;
//       [1456,2320) z 4-row blocks
__global__ __launch_bounds__(256) void k_pre(
        const float* __restrict__ in, const float* __restrict__ cb,
        const float* __restrict__ ze,
        unsigned long long* __restrict__ pats,
        float* __restrict__ scal,
        float* __restrict__ en,
        unsigned short* __restrict__ ehi, unsigned short* __restrict__ elo,
        unsigned short* __restrict__ zhi, unsigned short* __restrict__ zlo) {
    int bid = blockIdx.x;
    int t = threadIdx.x;
    if (bid < 432) {
        if (bid == 0 && t < 16) scal[t] = 0.0f;   // scal[0..7] + done counter
        __shared__ unsigned long long wpk[8];     // 512 voxels = 8 words
        if (t < 8) wpk[t] = 0ULL;
        __syncthreads();
        int v0i = bid * 512 + t * 2;              // 27 blocks per b (13824/512)
        int b = v0i / VOX;
        int r = v0i % VOX;
        const float* p = in + (size_t)b * NCH * VOX + r;
        float2 vals[NCH];
#pragma unroll
        for (int c = 0; c < NCH; ++c)
            vals[c] = *(const float2*)&p[(size_t)c * VOX];
        float m0 = vals[1].x, m1 = vals[1].y;
#pragma unroll
        for (int c = 2; c < NCH; ++c) {
            m0 = fmaxf(m0, vals[c].x);
            m1 = fmaxf(m1, vals[c].y);
        }
        unsigned long long bits = (m0 > vals[0].x ? 1ULL : 0ULL)
                                | (m1 > vals[0].y ? 2ULL : 0ULL);
        atomicOr(&wpk[t >> 5], bits << ((t & 31) * 2));
        __syncthreads();
        if (t < 8) pats[(bid * 512 >> 6) + t] = wpk[t];
        return;
    }
    __shared__ float ws[16];
    if (bid < 1456) {
        int k = bid - 432, c = t;
        float v = cb[k * C_DIM + c];
        float ss = v * v;
#pragma unroll
        for (int off = 32; off > 0; off >>= 1) ss += __shfl_down(ss, off, 64);
        if ((c & 63) == 0) ws[c >> 6] = ss;
        __syncthreads();
        float nrm = fmaxf(sqrtf(ws[0] + ws[1] + ws[2] + ws[3]), 1e-12f);
        float o = v / nrm;
        en[k * C_DIM + c] = o;
        unsigned short h = f2bf_rne(o);
        size_t off = swz(k, c);
        ehi[off] = h;
        elo[off] = f2bf_rne(o - bf2f(h));
    } else {
        // 4 rows per block via float4 over s (216 % 4 == 0 -> same b)
        int zb = bid - 1456;             // 0..863
        int n0 = zb * 4;
        int b = n0 / SPATIAL, s0 = n0 - b * SPATIAL;
        int c = t, w = t >> 6, lane = t & 63;
        float4 v4 = *(const float4*)&ze[((size_t)(b * C_DIM + c)) * SPATIAL + s0];
        float q0 = v4.x * v4.x, q1 = v4.y * v4.y, q2 = v4.z * v4.z, q3 = v4.w * v4.w;
#pragma unroll
        for (int off = 32; off > 0; off >>= 1) {
            q0 += __shfl_down(q0, off, 64);
            q1 += __shfl_down(q1, off, 64);
            q2 += __shfl_down(q2, off, 64);
            q3 += __shfl_down(q3, off, 64);
        }
        if (lane == 0) {
            ws[w * 4 + 0] = q0; ws[w * 4 + 1] = q1;
            ws[w * 4 + 2] = q2; ws[w * 4 + 3] = q3;
        }
        __syncthreads();
        float vv[4] = {v4.x, v4.y, v4.z, v4.w};
#pragma unroll
        for (int j = 0; j < 4; ++j) {
            float nrm = fmaxf(sqrtf(ws[j] + ws[4 + j] + ws[8 + j] + ws[12 + j]), 1e-12f);
            float o = vv[j] / nrm;
            unsigned short h = f2bf_rne(o);
            size_t off = swz(n0 + j, c);
            zhi[off] = h;
            zlo[off] = f2bf_rne(o - bf2f(h));
        }
    }
}

// ------------- K2: ONE fat kernel, 512 threads (8 waves), R4 body +
// (a) XCD role partition: hardware round-robins blockIdx%8 across XCDs, so
//     GEMM blocks are placed on XCDs {0,1} (L2 holds E+A only) and HAM
//     blocks on XCDs {2..7} (L2 holds zhi only) -- no cross-phase thrash.
// (b) per-block k-step rotation: desynchronizes the lockstep same-address
//     fragment streams across blocks (L2 bank/channel spread).
// Last of all 486 blocks computes avg-entropy + final loss.
__global__ __launch_bounds__(512) void k_fat(
        const unsigned short* __restrict__ zhi, const unsigned short* __restrict__ zlo,
        const unsigned short* __restrict__ ehi, const unsigned short* __restrict__ elo,
        const unsigned long long* __restrict__ pats,
        const float* __restrict__ en,
        float* __restrict__ avgp_part, float* __restrict__ scal,
        float* __restrict__ out) {
    __shared__ float zq[32 * 257];     // 32.9 KB transpose buffer
    __shared__ float sm[32][8];        // per-wave row max
    __shared__ int   si[32][8];        // per-wave row argmax
    __shared__ float sS[32][8];        // per-wave row sum(e)
    __shared__ float sT[32][8];        // per-wave row sum(e*d)
    __shared__ float gm[32];           // global row max
    __shared__ int   gmi[32];          // global row argmax
    __shared__ float invS[32];
    __shared__ float ws8[8];
    __shared__ float hw8[8], hd8[8];   // ham partials per wave
    __shared__ int lastflag;
    unsigned int* done = (unsigned int*)&scal[8];

    int t = threadIdx.x;
    int w = t >> 6, lane = t & 63;
    int half = lane >> 5, l31 = lane & 31;

    // ---- XCD-aware role remap (heuristic %8 round-robin; perf-only)
    int bid0 = blockIdx.x;
    int xcd = bid0 & 7, slot = bid0 >> 3;
    int bid;
    if (bid0 < 432) {
        if (xcd < 2) bid = slot * 2 + xcd;               // 108 GEMM on XCD 0,1
        else         bid = N_GBLK + slot * 6 + (xcd - 2); // 324 HAM on XCD 2..7
    } else {
        bid = N_GBLK + 324 + (bid0 - 432);               // last 54 HAM anywhere
    }

    const bf16x8* __restrict__ Zh = (const bf16x8*)zhi;   // [strip][1024 chunks]
    const bf16x8* __restrict__ Zl = (const bf16x8*)zlo;
    const bf16x8* __restrict__ Eh = (const bf16x8*)ehi;
    const bf16x8* __restrict__ El = (const bf16x8*)elo;

    if (bid < N_GBLK) {
        // ===== fused GEMM + stats: rows [bid*32, bid*32+32) x cols [0,1024)
        int sa = bid;                  // A strip (32 rows)
        int n0 = bid * 32;
        int boff = (bid * 5) & 15;     // per-block k-rotation

        f32x16 acc[4];
#pragma unroll
        for (int q = 0; q < 4; ++q)
#pragma unroll
            for (int e = 0; e < 16; ++e) acc[q][e] = 0.0f;

#pragma unroll
        for (int s = 0; s < 16; ++s) {          // 16 k-steps of 16, rotated
            int s16 = (s + boff) & 15;
            int u = s16 * 64 + lane;
            bf16x8 ah = Zh[(size_t)sa * 1024 + u];
            bf16x8 al = Zl[(size_t)sa * 1024 + u];
            bf16x8 bh[4], bl[4];
#pragma unroll
            for (int q = 0; q < 4; ++q) {
                bh[q] = Eh[(size_t)(w * 4 + q) * 1024 + u];
                bl[q] = El[(size_t)(w * 4 + q) * 1024 + u];
            }
#pragma unroll
            for (int q = 0; q < 4; ++q) {
                acc[q] = __builtin_amdgcn_mfma_f32_32x32x16_bf16(ah, bh[q], acc[q], 0, 0, 0);
                acc[q] = __builtin_amdgcn_mfma_f32_32x32x16_bf16(ah, bl[q], acc[q], 0, 0, 0);
                acc[q] = __builtin_amdgcn_mfma_f32_32x32x16_bf16(al, bh[q], acc[q], 0, 0, 0);
            }
        }
        // C/D layout (m74/m101): col = w*128 + q*32 + l31,
        //                        row = (g&3)+8*(g>>2)+4*half

        // --- P1: per-wave row max+argmax over this wave's 128-col slice
#pragma unroll
        for (int g = 0; g < 16; ++g) {
            float m = acc[0][g];
            int mi = w * 128 + l31;
#pragma unroll
            for (int q = 1; q < 4; ++q) {
                float x = acc[q][g];
                int c = w * 128 + q * 32 + l31;
                if (x > m) { m = x; mi = c; }
            }
#pragma unroll
            for (int mask = 1; mask < 32; mask <<= 1) {
                float vo = __shfl_xor(m, mask, 64);
                int   io = __shfl_xor(mi, mask, 64);
                if (vo > m || (vo == m && io < mi)) { m = vo; mi = io; }
            }
            int row = (g & 3) + 8 * (g >> 2) + 4 * half;
            if (l31 == 0) { sm[row][w] = m; si[row][w] = mi; }
        }
        __syncthreads();

        // --- P2: merge across waves -> global row max/idx; idx out; commit
        float cmv = 0.0f;
        if (t < 32) {
            float m = sm[t][0];
            int mi = si[t][0];
#pragma unroll
            for (int ww = 1; ww < 8; ++ww) {
                float mw = sm[t][ww];
                int miw = si[t][ww];
                if (mw > m || (mw == m && miw < mi)) { m = mw; mi = miw; }
            }
            gm[t] = m; gmi[t] = mi;
            out[884737 + n0 + t] = (float)mi;
            cmv = 2.0f - 2.0f * m;
        }
        if (w == 0) {
#pragma unroll
            for (int off = 32; off > 0; off >>= 1) cmv += __shfl_down(cmv, off, 64);
            if (lane == 0) atomicAdd(&scal[1], cmv);
        }
        __syncthreads();

        // --- P3: exp relative to global max; per-wave S,T partials; overwrite
        //         acc with e.  Also gather en[argmax] rows into zq.
#pragma unroll
        for (int g = 0; g < 16; ++g) {
            int row = (g & 3) + 8 * (g >> 2) + 4 * half;
            float gmr = gm[row];
            float S = 0.0f, T = 0.0f;
#pragma unroll
            for (int q = 0; q < 4; ++q) {
                float d = 100.0f * (acc[q][g] - gmr);
                float ee = __expf(d);
                S += ee; T += ee * d;
                acc[q][g] = ee;
            }
#pragma unroll
            for (int mask = 1; mask < 32; mask <<= 1) {
                S += __shfl_xor(S, mask, 64);
                T += __shfl_xor(T, mask, 64);
            }
            if (l31 == 0) { sS[row][w] = S; sT[row][w] = T; }
        }
#pragma unroll
        for (int rr = 0; rr < 4; ++rr) {
            int row = w * 4 + rr;
            int mi = gmi[row];
            float4 g4 = *(const float4*)&en[(size_t)mi * C_DIM + lane * 4];
            zq[row * 257 + lane * 4 + 0] = g4.x;
            zq[row * 257 + lane * 4 + 1] = g4.y;
            zq[row * 257 + lane * 4 + 2] = g4.z;
            zq[row * 257 + lane * 4 + 3] = g4.w;
        }
        __syncthreads();

        // --- P4a: merge S,T across waves; sample-entropy contribution
        float sev = 0.0f;
        if (t < 32) {
            float S = 0.0f, T = 0.0f;
#pragma unroll
            for (int ww = 0; ww < 8; ++ww) { S += sS[t][ww]; T += sT[t][ww]; }
            float iv = 1.0f / S;
            invS[t] = iv;
            sev = logf(S) - T * iv;
        }
        if (w == 0) {
#pragma unroll
            for (int off = 32; off > 0; off >>= 1) sev += __shfl_down(sev, off, 64);
            if (lane == 0) atomicAdd(&scal[0], sev);
        }
        __syncthreads();

        // --- P4b: per-block avgp partial: col sums of probs over 32 rows
        {
            float cs[4] = {0.0f, 0.0f, 0.0f, 0.0f};
#pragma unroll
            for (int g = 0; g < 16; ++g) {
                int row = (g & 3) + 8 * (g >> 2) + 4 * half;
                float iv = invS[row];
#pragma unroll
                for (int q = 0; q < 4; ++q) cs[q] += acc[q][g] * iv;
            }
#pragma unroll
            for (int q = 0; q < 4; ++q) cs[q] += __shfl_xor(cs[q], 32, 64);
            if (half == 0) {
#pragma unroll
                for (int q = 0; q < 4; ++q)
                    avgp_part[(size_t)bid * K_CB + w * 128 + q * 32 + l31] = cs[q];
            }
        }

        // --- P5: z_q scatter from zq. thread t -> (row rl = t&31, cols cg*16..)
        {
            int rl = t & 31, cg = t >> 5;
            int n = n0 + rl;
            int b = n / SPATIAL, s = n - b * SPATIAL;
            size_t obase = ((size_t)b * C_DIM) * SPATIAL + s;
#pragma unroll
            for (int cc = 0; cc < 16; ++cc) {
                int c = cg * 16 + cc;
                out[obase + (size_t)c * SPATIAL] = zq[rl * 257 + c];
            }
        }
    } else {
        // ===== HAM branch: pairwise Gram, upper-tri 128x128 tiles.
        // 8 waves: wave w = (i-strip iw = w&3, k-half kh = w>>2), k rotated.
        int hb = bid - N_GBLK;           // 0..377
        int ti = 0, rem = hb;
        while (rem >= 27 - ti) { rem -= 27 - ti; ++ti; }
        int tj = ti + rem;
        int i0 = ti * 128, j0 = tj * 128;
        float factor = (ti == tj) ? 1.0f : 2.0f;
        int iw = w & 3, kh = w >> 2;
        int sib = ti * 4 + iw;           // A strip for this wave (32 rows)
        int sjb = tj * 4;                // B strips (4)
        int hoff = hb & 7;               // per-block k-rotation

        f32x16 acc[4];
#pragma unroll
        for (int c = 0; c < 4; ++c)
#pragma unroll
            for (int e = 0; e < 16; ++e) acc[c][e] = 0.0f;

#pragma unroll
        for (int s8 = 0; s8 < 8; ++s8) {     // this wave's k-half, rotated
            int u = (kh * 8 + ((s8 + hoff) & 7)) * 64 + lane;
            bf16x8 a0 = Zh[(size_t)sib * 1024 + u];
            bf16x8 bf[4];
#pragma unroll
            for (int c = 0; c < 4; ++c)
                bf[c] = Zh[(size_t)(sjb + c) * 1024 + u];
#pragma unroll
            for (int c = 0; c < 4; ++c)
                acc[c] = __builtin_amdgcn_mfma_f32_32x32x16_bf16(a0, bf[c], acc[c], 0, 0, 0);
        }

        unsigned long long pj[4];
#pragma unroll
        for (int c = 0; c < 4; ++c) pj[c] = pats[j0 + c * 32 + l31];

        float sW = 0.0f, sD = 0.0f;
        int ibase = i0 + iw * 32 + 4 * half;
#pragma unroll
        for (int g = 0; g < 16; ++g) {
            int gi = ibase + (g & 3) + 8 * (g >> 2);
            unsigned long long pi = pats[gi];
#pragma unroll
            for (int c = 0; c < 4; ++c) {
                int gj = j0 + c * 32 + l31;
                int pop = __popcll(pi ^ pj[c]);
                float wgt = (pop <= 5 && gi != gj) ? (1.0f - (float)pop * 0.015625f) : 0.0f;
                sW += wgt;
                sD += wgt * acc[c][g];
            }
        }
#pragma unroll
        for (int off = 32; off > 0; off >>= 1) {
            sW += __shfl_down(sW, off, 64);
            sD += __shfl_down(sD, off, 64);
        }
        if (lane == 0) { hw8[w] = sW; hd8[w] = sD; }
        __syncthreads();
        if (t == 0) {
            float W = hw8[0] + hw8[1] + hw8[2] + hw8[3];   // kh==0 only
            float D = hd8[0] + hd8[1] + hd8[2] + hd8[3]
                    + hd8[4] + hd8[5] + hd8[6] + hd8[7];
            atomicAdd(&scal[2], factor * W);
            atomicAdd(&scal[3], factor * D);
        }
    }

    // ===== common: done counter + last-block final loss
    __syncthreads();
    if (t == 0) {
        __threadfence();
        unsigned int old = atomicAdd(done, 1u);
        lastflag = (old == N_FBLK - 1) ? 1 : 0;
    }
    __syncthreads();
    if (lastflag) {
        __threadfence();
        int col0 = t, col1 = t + 512;
        float p0 = 0.0f, p1 = 0.0f, p2 = 0.0f, p3 = 0.0f;
        float q0 = 0.0f, q1 = 0.0f, q2 = 0.0f, q3 = 0.0f;
        for (int bb = 0; bb < N_GBLK; bb += 4) {   // 8 independent load streams
            p0 += avgp_part[(size_t)(bb + 0) * K_CB + col0];
            p1 += avgp_part[(size_t)(bb + 1) * K_CB + col0];
            p2 += avgp_part[(size_t)(bb + 2) * K_CB + col0];
            p3 += avgp_part[(size_t)(bb + 3) * K_CB + col0];
            q0 += avgp_part[(size_t)(bb + 0) * K_CB + col1];
            q1 += avgp_part[(size_t)(bb + 1) * K_CB + col1];
            q2 += avgp_part[(size_t)(bb + 2) * K_CB + col1];
            q3 += avgp_part[(size_t)(bb + 3) * K_CB + col1];
        }
        float ap0 = (p0 + p1 + p2 + p3) * (1.0f / N_ROWS);
        float ap1 = (q0 + q1 + q2 + q3) * (1.0f / N_ROWS);
        float term = ap0 * logf(ap0 + 1e-5f) + ap1 * logf(ap1 + 1e-5f);
#pragma unroll
        for (int off = 32; off > 0; off >>= 1) term += __shfl_down(term, off, 64);
        if (lane == 0) ws8[w] = term;
        __syncthreads();
        if (t == 0) {
            float sAP = 0.0f;
#pragma unroll
            for (int i = 0; i < 8; ++i) sAP += ws8[i];
            float s0 = atomicAdd(&scal[0], 0.0f);
            float s1 = atomicAdd(&scal[1], 0.0f);
            float s2 = atomicAdd(&scal[2], 0.0f);
            float s3 = atomicAdd(&scal[3], 0.0f);
            float sample = s0 * (1.0f / N_ROWS);
            float commit = s1 * (1.0f / ((float)N_ROWS * C_DIM));
            float ent = 0.1f * (sample + sAP);
            float ham = (s2 - s3) / (s2 + 1e-8f);
            out[884736] = 1.25f * commit + ent + ham;
        }
    }
}

// ----------------------------------------------------------------- launch
extern "C" void kernel_launch(void* const* d_in, const int* in_sizes, int n_in,
                              void* d_out, int out_size, void* d_ws, size_t ws_size,
                              hipStream_t stream) {
    const float* in_blocks = (const float*)d_in[0];  // [16,32,24,24,24]
    const float* z_e       = (const float*)d_in[1];  // [16,256,6,6,6]
    const float* cb        = (const float*)d_in[2];  // [1024,256]
    float* out = (float*)d_out;  // [884736 z_q][1 loss][3456 idx]

    char* ws = (char*)d_ws;
    float* en   = (float*)(ws + 0);                  //  1,048,576 B
    unsigned short* zhi = (unsigned short*)(ws + 15204352);  // 1,769,472 B (swizzled)
    unsigned short* zlo = (unsigned short*)(ws + 16973824);  // 1,769,472 B (swizzled)
    unsigned short* ehi = (unsigned short*)(ws + 18743296);  //   524,288 B (swizzled)
    unsigned short* elo = (unsigned short*)(ws + 19267584);  //   524,288 B (swizzled)
    unsigned long long* pats = (unsigned long long*)(ws + 19791872); // 27,648 B
    float* avgp_part = (float*)(ws + 19819520);      // 108*4096 = 442,368 B
    float* scal = (float*)(ws + 20704256);           // 64 B (scal[0..7] + done)

    k_pre<<<2320, 256, 0, stream>>>(in_blocks, cb, z_e, pats, scal,
                                    en, ehi, elo, zhi, zlo);
    k_fat<<<N_FBLK, 512, 0, stream>>>(zhi, zlo, ehi, elo, pats, en,
                                      avgp_part, scal, out);
}

// Round 9
// 136.468 us; speedup vs baseline: 1.1269x; 1.1269x over previous
//
#include <hip/hip_runtime.h>
#include <cstdint>
#include <cstddef>

#define N_ROWS 3456   // 16*216 chunks
#define C_DIM 256
#define K_CB 1024
#define B_SZ 16
#define SPATIAL 216
#define VOX 13824     // 24*24*24
#define NCH 32
#define N_GBLK 108    // fused gemm+stat blocks (32 rows x 1024 cols each)
#define N_FBLK 486    // 108 gemm + 378 ham

typedef __attribute__((ext_vector_type(16))) float f32x16;
typedef __attribute__((ext_vector_type(8))) short bf16x8;

__device__ __forceinline__ unsigned short f2bf_rne(float f) {
    unsigned int u = __float_as_uint(f);
    u += 0x7FFFu + ((u >> 16) & 1u);
    return (unsigned short)(u >> 16);
}
__device__ __forceinline__ float bf2f(unsigned short h) {
    unsigned int u = ((unsigned int)h) << 16;
    return __uint_as_float(u);
}

// Swizzled fragment layout: element (row n, col c) of a [rows x 256] matrix
// lives at  strip(n>>5)*8192 + (c>>3)*256 + (n&31)*8 + (c&7).
__device__ __forceinline__ size_t swz(int n, int c) {
    return (size_t)(n >> 5) * 8192 + (size_t)((c >> 3) * 256) + (size_t)((n & 31) * 8) + (c & 7);
}

// ---------------- K1: fused preprocessing: patterns + init + cb/z norm+split
// grid: [0,432) patterns (2 voxels/thread, float2) ; [432,1456) codebook ;
//       [1456,2320) z 4-row blocks
__global__ __launch_bounds__(256) void k_pre(
        const float* __restrict__ in, const float* __restrict__ cb,
        const float* __restrict__ ze,
        unsigned long long* __restrict__ pats,
        float* __restrict__ scal,
        float* __restrict__ en,
        unsigned short* __restrict__ ehi, unsigned short* __restrict__ elo,
        unsigned short* __restrict__ zhi, unsigned short* __restrict__ zlo) {
    int bid = blockIdx.x;
    int t = threadIdx.x;
    if (bid < 432) {
        if (bid == 0 && t < 16) scal[t] = 0.0f;   // scal[0..7] + done counter
        __shared__ unsigned long long wpk[8];     // 512 voxels = 8 words
        if (t < 8) wpk[t] = 0ULL;
        __syncthreads();
        int v0i = bid * 512 + t * 2;              // 27 blocks per b (13824/512)
        int b = v0i / VOX;
        int r = v0i % VOX;
        const float* p = in + (size_t)b * NCH * VOX + r;
        float2 vals[NCH];
#pragma unroll
        for (int c = 0; c < NCH; ++c)
            vals[c] = *(const float2*)&p[(size_t)c * VOX];
        float m0 = vals[1].x, m1 = vals[1].y;
#pragma unroll
        for (int c = 2; c < NCH; ++c) {
            m0 = fmaxf(m0, vals[c].x);
            m1 = fmaxf(m1, vals[c].y);
        }
        unsigned long long bits = (m0 > vals[0].x ? 1ULL : 0ULL)
                                | (m1 > vals[0].y ? 2ULL : 0ULL);
        atomicOr(&wpk[t >> 5], bits << ((t & 31) * 2));
        __syncthreads();
        if (t < 8) pats[(bid * 512 >> 6) + t] = wpk[t];
        return;
    }
    __shared__ float ws[16];
    if (bid < 1456) {
        int k = bid - 432, c = t;
        float v = cb[k * C_DIM + c];
        float ss = v * v;
#pragma unroll
        for (int off = 32; off > 0; off >>= 1) ss += __shfl_down(ss, off, 64);
        if ((c & 63) == 0) ws[c >> 6] = ss;
        __syncthreads();
        float nrm = fmaxf(sqrtf(ws[0] + ws[1] + ws[2] + ws[3]), 1e-12f);
        float o = v / nrm;
        en[k * C_DIM + c] = o;
        unsigned short h = f2bf_rne(o);
        size_t off = swz(k, c);
        ehi[off] = h;
        elo[off] = f2bf_rne(o - bf2f(h));
    } else {
        // 4 rows per block via float4 over s (216 % 4 == 0 -> same b)
        int zb = bid - 1456;             // 0..863
        int n0 = zb * 4;
        int b = n0 / SPATIAL, s0 = n0 - b * SPATIAL;
        int c = t, w = t >> 6, lane = t & 63;
        float4 v4 = *(const float4*)&ze[((size_t)(b * C_DIM + c)) * SPATIAL + s0];
        float q0 = v4.x * v4.x, q1 = v4.y * v4.y, q2 = v4.z * v4.z, q3 = v4.w * v4.w;
#pragma unroll
        for (int off = 32; off > 0; off >>= 1) {
            q0 += __shfl_down(q0, off, 64);
            q1 += __shfl_down(q1, off, 64);
            q2 += __shfl_down(q2, off, 64);
            q3 += __shfl_down(q3, off, 64);
        }
        if (lane == 0) {
            ws[w * 4 + 0] = q0; ws[w * 4 + 1] = q1;
            ws[w * 4 + 2] = q2; ws[w * 4 + 3] = q3;
        }
        __syncthreads();
        float vv[4] = {v4.x, v4.y, v4.z, v4.w};
#pragma unroll
        for (int j = 0; j < 4; ++j) {
            float nrm = fmaxf(sqrtf(ws[j] + ws[4 + j] + ws[8 + j] + ws[12 + j]), 1e-12f);
            float o = vv[j] / nrm;
            unsigned short h = f2bf_rne(o);
            size_t off = swz(n0 + j, c);
            zhi[off] = h;
            zlo[off] = f2bf_rne(o - bf2f(h));
        }
    }
}

// ------------- K2: ONE fat kernel, 1024 threads = 16 waves per block.
// blocks [0,108): fused affinity GEMM + stats.  Wave (cg = w&7, kh = w>>3):
//   cols [cg*128, +128), k-half kh -> only 8 serial k-steps per wave (the
//   16-step chain was the measured straggler).  kh=1 partial accs merge into
//   kh=0 via LDS (GEMM is linear in k).  Stats phases run on the 8 kh=0
//   waves exactly as the proven R4 code.
// blocks [108,486): hamming Gram tiles; wave (iw = w&3, kq = w>>2): k-quarter
//   split, 4 steps/wave (Gram linear in k).
// Last of all 486 blocks computes avg-entropy + final loss.
__global__ __launch_bounds__(1024) void k_fat(
        const unsigned short* __restrict__ zhi, const unsigned short* __restrict__ zlo,
        const unsigned short* __restrict__ ehi, const unsigned short* __restrict__ elo,
        const unsigned long long* __restrict__ pats,
        const float* __restrict__ en,
        float* __restrict__ avgp_part, float* __restrict__ scal,
        float* __restrict__ out) {
    __shared__ float mrg[16384];       // 64 KB merge buffer; reused as zq
    __shared__ float sm[32][8];        // per-colgroup row max
    __shared__ int   si[32][8];        // per-colgroup row argmax
    __shared__ float sS[32][8];        // per-colgroup row sum(e)
    __shared__ float sT[32][8];        // per-colgroup row sum(e*d)
    __shared__ float gm[32];           // global row max
    __shared__ int   gmi[32];          // global row argmax
    __shared__ float invS[32];
    __shared__ float ws16[16];
    __shared__ float hw16[16], hd16[16];  // ham partials per wave
    __shared__ int lastflag;
    unsigned int* done = (unsigned int*)&scal[8];
    float* zq = mrg;                   // 32*257 floats <= 16384

    int t = threadIdx.x;
    int w = t >> 6, lane = t & 63;     // w = 0..15
    int half = lane >> 5, l31 = lane & 31;
    int bid = blockIdx.x;
    const bf16x8* __restrict__ Zh = (const bf16x8*)zhi;   // [strip][1024 chunks]
    const bf16x8* __restrict__ Zl = (const bf16x8*)zlo;
    const bf16x8* __restrict__ Eh = (const bf16x8*)ehi;
    const bf16x8* __restrict__ El = (const bf16x8*)elo;

    if (bid < N_GBLK) {
        // ===== fused GEMM + stats: rows [bid*32, bid*32+32) x cols [0,1024)
        int sa = bid;                  // A strip (32 rows)
        int n0 = bid * 32;
        int cg = w & 7, kh = w >> 3;   // col-group, k-half

        f32x16 acc[4];
#pragma unroll
        for (int q = 0; q < 4; ++q)
#pragma unroll
            for (int e = 0; e < 16; ++e) acc[q][e] = 0.0f;

#pragma unroll
        for (int s = 0; s < 8; ++s) {           // this wave's k-half: 8 steps
            int u = (kh * 8 + s) * 64 + lane;
            bf16x8 ah = Zh[(size_t)sa * 1024 + u];
            bf16x8 al = Zl[(size_t)sa * 1024 + u];
            bf16x8 bh[4], bl[4];
#pragma unroll
            for (int q = 0; q < 4; ++q) {
                bh[q] = Eh[(size_t)(cg * 4 + q) * 1024 + u];
                bl[q] = El[(size_t)(cg * 4 + q) * 1024 + u];
            }
#pragma unroll
            for (int q = 0; q < 4; ++q) {
                acc[q] = __builtin_amdgcn_mfma_f32_32x32x16_bf16(ah, bh[q], acc[q], 0, 0, 0);
                acc[q] = __builtin_amdgcn_mfma_f32_32x32x16_bf16(ah, bl[q], acc[q], 0, 0, 0);
                acc[q] = __builtin_amdgcn_mfma_f32_32x32x16_bf16(al, bh[q], acc[q], 0, 0, 0);
            }
        }

        // --- k-half merge: kh=1 publishes, kh=0 accumulates (2 rounds, 64 KB)
#pragma unroll
        for (int par = 0; par < 2; ++par) {
            if (kh == 1 && (cg & 1) == par) {
                int slot = cg >> 1;    // 0..3
#pragma unroll
                for (int q = 0; q < 4; ++q)
#pragma unroll
                    for (int g = 0; g < 16; ++g)
                        mrg[slot * 4096 + (q * 16 + g) * 64 + lane] = acc[q][g];
            }
            __syncthreads();
            if (kh == 0 && (cg & 1) == par) {
                int slot = cg >> 1;
#pragma unroll
                for (int q = 0; q < 4; ++q)
#pragma unroll
                    for (int g = 0; g < 16; ++g)
                        acc[q][g] += mrg[slot * 4096 + (q * 16 + g) * 64 + lane];
            }
            __syncthreads();
        }
        // From here, kh=0 waves (w = cg < 8) hold the full acc.
        // C/D layout (m74/m101): col = cg*128 + q*32 + l31,
        //                        row = (g&3)+8*(g>>2)+4*half

        // --- P1: per-colgroup row max+argmax over its 128-col slice
        if (w < 8) {
#pragma unroll
            for (int g = 0; g < 16; ++g) {
                float m = acc[0][g];
                int mi = cg * 128 + l31;
#pragma unroll
                for (int q = 1; q < 4; ++q) {
                    float x = acc[q][g];
                    int c = cg * 128 + q * 32 + l31;
                    if (x > m) { m = x; mi = c; }
                }
#pragma unroll
                for (int mask = 1; mask < 32; mask <<= 1) {
                    float vo = __shfl_xor(m, mask, 64);
                    int   io = __shfl_xor(mi, mask, 64);
                    if (vo > m || (vo == m && io < mi)) { m = vo; mi = io; }
                }
                int row = (g & 3) + 8 * (g >> 2) + 4 * half;
                if (l31 == 0) { sm[row][cg] = m; si[row][cg] = mi; }
            }
        }
        __syncthreads();

        // --- P2: merge across colgroups -> global row max/idx; idx; commit
        float cmv = 0.0f;
        if (t < 32) {
            float m = sm[t][0];
            int mi = si[t][0];
#pragma unroll
            for (int ww = 1; ww < 8; ++ww) {
                float mw = sm[t][ww];
                int miw = si[t][ww];
                if (mw > m || (mw == m && miw < mi)) { m = mw; mi = miw; }
            }
            gm[t] = m; gmi[t] = mi;
            out[884737 + n0 + t] = (float)mi;
            cmv = 2.0f - 2.0f * m;
        }
        if (w == 0) {
#pragma unroll
            for (int off = 32; off > 0; off >>= 1) cmv += __shfl_down(cmv, off, 64);
            if (lane == 0) atomicAdd(&scal[1], cmv);
        }
        __syncthreads();

        // --- P3: exp relative to global max; per-colgroup S,T partials;
        //         overwrite acc with e.  Gather en[argmax] rows into zq.
        if (w < 8) {
#pragma unroll
            for (int g = 0; g < 16; ++g) {
                int row = (g & 3) + 8 * (g >> 2) + 4 * half;
                float gmr = gm[row];
                float S = 0.0f, T = 0.0f;
#pragma unroll
                for (int q = 0; q < 4; ++q) {
                    float d = 100.0f * (acc[q][g] - gmr);
                    float ee = __expf(d);
                    S += ee; T += ee * d;
                    acc[q][g] = ee;
                }
#pragma unroll
                for (int mask = 1; mask < 32; mask <<= 1) {
                    S += __shfl_xor(S, mask, 64);
                    T += __shfl_xor(T, mask, 64);
                }
                if (l31 == 0) { sS[row][cg] = S; sT[row][cg] = T; }
            }
#pragma unroll
            for (int rr = 0; rr < 4; ++rr) {
                int row = cg * 4 + rr;
                int mi = gmi[row];
                float4 g4 = *(const float4*)&en[(size_t)mi * C_DIM + lane * 4];
                zq[row * 257 + lane * 4 + 0] = g4.x;
                zq[row * 257 + lane * 4 + 1] = g4.y;
                zq[row * 257 + lane * 4 + 2] = g4.z;
                zq[row * 257 + lane * 4 + 3] = g4.w;
            }
        }
        __syncthreads();

        // --- P4a: merge S,T across colgroups; sample-entropy contribution
        float sev = 0.0f;
        if (t < 32) {
            float S = 0.0f, T = 0.0f;
#pragma unroll
            for (int ww = 0; ww < 8; ++ww) { S += sS[t][ww]; T += sT[t][ww]; }
            float iv = 1.0f / S;
            invS[t] = iv;
            sev = logf(S) - T * iv;
        }
        if (w == 0) {
#pragma unroll
            for (int off = 32; off > 0; off >>= 1) sev += __shfl_down(sev, off, 64);
            if (lane == 0) atomicAdd(&scal[0], sev);
        }
        __syncthreads();

        // --- P4b: per-block avgp partial: col sums of probs over 32 rows
        if (w < 8) {
            float cs[4] = {0.0f, 0.0f, 0.0f, 0.0f};
#pragma unroll
            for (int g = 0; g < 16; ++g) {
                int row = (g & 3) + 8 * (g >> 2) + 4 * half;
                float iv = invS[row];
#pragma unroll
                for (int q = 0; q < 4; ++q) cs[q] += acc[q][g] * iv;
            }
#pragma unroll
            for (int q = 0; q < 4; ++q) cs[q] += __shfl_xor(cs[q], 32, 64);
            if (half == 0) {
#pragma unroll
                for (int q = 0; q < 4; ++q)
                    avgp_part[(size_t)bid * K_CB + cg * 128 + q * 32 + l31] = cs[q];
            }
        }

        // --- P5: z_q scatter from zq: thread t -> (row rl = t&31, cols cg32*8..)
        {
            int rl = t & 31, cg32 = t >> 5;   // cg32 = 0..31
            int n = n0 + rl;
            int b = n / SPATIAL, s = n - b * SPATIAL;
            size_t obase = ((size_t)b * C_DIM) * SPATIAL + s;
#pragma unroll
            for (int cc = 0; cc < 8; ++cc) {
                int c = cg32 * 8 + cc;
                out[obase + (size_t)c * SPATIAL] = zq[rl * 257 + c];
            }
        }
    } else {
        // ===== HAM branch: pairwise Gram, upper-tri 128x128 tiles.
        // 16 waves: wave (iw = w&3, kq = w>>2): 4 k-steps each.
        int hb = bid - N_GBLK;           // 0..377
        int ti = 0, rem = hb;
        while (rem >= 27 - ti) { rem -= 27 - ti; ++ti; }
        int tj = ti + rem;
        int i0 = ti * 128, j0 = tj * 128;
        float factor = (ti == tj) ? 1.0f : 2.0f;
        int iw = w & 3, kq = w >> 2;
        int sib = ti * 4 + iw;           // A strip for this wave (32 rows)
        int sjb = tj * 4;                // B strips (4)

        f32x16 acc[4];
#pragma unroll
        for (int c = 0; c < 4; ++c)
#pragma unroll
            for (int e = 0; e < 16; ++e) acc[c][e] = 0.0f;

#pragma unroll
        for (int s4 = 0; s4 < 4; ++s4) {     // this wave's k-quarter
            int u = (kq * 4 + s4) * 64 + lane;
            bf16x8 a0 = Zh[(size_t)sib * 1024 + u];
            bf16x8 bf[4];
#pragma unroll
            for (int c = 0; c < 4; ++c)
                bf[c] = Zh[(size_t)(sjb + c) * 1024 + u];
#pragma unroll
            for (int c = 0; c < 4; ++c)
                acc[c] = __builtin_amdgcn_mfma_f32_32x32x16_bf16(a0, bf[c], acc[c], 0, 0, 0);
        }

        unsigned long long pj[4];
#pragma unroll
        for (int c = 0; c < 4; ++c) pj[c] = pats[j0 + c * 32 + l31];

        float sW = 0.0f, sD = 0.0f;
        int ibase = i0 + iw * 32 + 4 * half;
#pragma unroll
        for (int g = 0; g < 16; ++g) {
            int gi = ibase + (g & 3) + 8 * (g >> 2);
            unsigned long long pi = pats[gi];
#pragma unroll
            for (int c = 0; c < 4; ++c) {
                int gj = j0 + c * 32 + l31;
                int pop = __popcll(pi ^ pj[c]);
                float wgt = (pop <= 5 && gi != gj) ? (1.0f - (float)pop * 0.015625f) : 0.0f;
                sW += wgt;
                sD += wgt * acc[c][g];
            }
        }
#pragma unroll
        for (int off = 32; off > 0; off >>= 1) {
            sW += __shfl_down(sW, off, 64);
            sD += __shfl_down(sD, off, 64);
        }
        if (lane == 0) { hw16[w] = sW; hd16[w] = sD; }
        __syncthreads();
        if (t == 0) {
            float W = hw16[0] + hw16[1] + hw16[2] + hw16[3];   // kq==0 only
            float D = 0.0f;
#pragma unroll
            for (int i = 0; i < 16; ++i) D += hd16[i];
            atomicAdd(&scal[2], factor * W);
            atomicAdd(&scal[3], factor * D);
        }
    }

    // ===== common: done counter + last-block final loss
    __syncthreads();
    if (t == 0) {
        __threadfence();
        unsigned int old = atomicAdd(done, 1u);
        lastflag = (old == N_FBLK - 1) ? 1 : 0;
    }
    __syncthreads();
    if (lastflag) {
        __threadfence();
        int col = t;                     // 1024 threads = 1024 cols
        float p0 = 0.0f, p1 = 0.0f, p2 = 0.0f, p3 = 0.0f;
        for (int bb = 0; bb < N_GBLK; bb += 4) {   // 4 independent load streams
            p0 += avgp_part[(size_t)(bb + 0) * K_CB + col];
            p1 += avgp_part[(size_t)(bb + 1) * K_CB + col];
            p2 += avgp_part[(size_t)(bb + 2) * K_CB + col];
            p3 += avgp_part[(size_t)(bb + 3) * K_CB + col];
        }
        float ap = (p0 + p1 + p2 + p3) * (1.0f / N_ROWS);
        float term = ap * logf(ap + 1e-5f);
#pragma unroll
        for (int off = 32; off > 0; off >>= 1) term += __shfl_down(term, off, 64);
        if (lane == 0) ws16[w] = term;
        __syncthreads();
        if (t == 0) {
            float sAP = 0.0f;
#pragma unroll
            for (int i = 0; i < 16; ++i) sAP += ws16[i];
            float s0 = atomicAdd(&scal[0], 0.0f);
            float s1 = atomicAdd(&scal[1], 0.0f);
            float s2 = atomicAdd(&scal[2], 0.0f);
            float s3 = atomicAdd(&scal[3], 0.0f);
            float sample = s0 * (1.0f / N_ROWS);
            float commit = s1 * (1.0f / ((float)N_ROWS * C_DIM));
            float ent = 0.1f * (sample + sAP);
            float ham = (s2 - s3) / (s2 + 1e-8f);
            out[884736] = 1.25f * commit + ent + ham;
        }
    }
}

// ----------------------------------------------------------------- launch
extern "C" void kernel_launch(void* const* d_in, const int* in_sizes, int n_in,
                              void* d_out, int out_size, void* d_ws, size_t ws_size,
                              hipStream_t stream) {
    const float* in_blocks = (const float*)d_in[0];  // [16,32,24,24,24]
    const float* z_e       = (const float*)d_in[1];  // [16,256,6,6,6]
    const float* cb        = (const float*)d_in[2];  // [1024,256]
    float* out = (float*)d_out;  // [884736 z_q][1 loss][3456 idx]

    char* ws = (char*)d_ws;
    float* en   = (float*)(ws + 0);                  //  1,048,576 B
    unsigned short* zhi = (unsigned short*)(ws + 15204352);  // 1,769,472 B (swizzled)
    unsigned short* zlo = (unsigned short*)(ws + 16973824);  // 1,769,472 B (swizzled)
    unsigned short* ehi = (unsigned short*)(ws + 18743296);  //   524,288 B (swizzled)
    unsigned short* elo = (unsigned short*)(ws + 19267584);  //   524,288 B (swizzled)
    unsigned long long* pats = (unsigned long long*)(ws + 19791872); // 27,648 B
    float* avgp_part = (float*)(ws + 19819520);      // 108*4096 = 442,368 B
    float* scal = (float*)(ws + 20704256);           // 64 B (scal[0..7] + done)

    k_pre<<<2320, 256, 0, stream>>>(in_blocks, cb, z_e, pats, scal,
                                    en, ehi, elo, zhi, zlo);
    k_fat<<<N_FBLK, 1024, 0, stream>>>(zhi, zlo, ehi, elo, pats, en,
                                       avgp_part, scal, out);
}

// Round 10
// 129.187 us; speedup vs baseline: 1.1904x; 1.0564x over previous
//
#include <hip/hip_runtime.h>
#include <cstdint>
#include <cstddef>

#define N_ROWS 3456   // 16*216 chunks
#define C_DIM 256
#define K_CB 1024
#define B_SZ 16
#define SPATIAL 216
#define VOX 13824     // 24*24*24
#define NCH 32
#define N_GBLK 108    // fused gemm+stat blocks (32 rows x 1024 cols each)
#define N_FBLK 486    // 108 gemm + 378 ham

typedef __attribute__((ext_vector_type(16))) float f32x16;
typedef __attribute__((ext_vector_type(8))) short bf16x8;

__device__ __forceinline__ unsigned short f2bf_rne(float f) {
    unsigned int u = __float_as_uint(f);
    u += 0x7FFFu + ((u >> 16) & 1u);
    return (unsigned short)(u >> 16);
}
__device__ __forceinline__ float bf2f(unsigned short h) {
    unsigned int u = ((unsigned int)h) << 16;
    return __uint_as_float(u);
}

// Swizzled fragment layout: element (row n, col c) of a [rows x 256] matrix
// lives at  strip(n>>5)*8192 + (c>>3)*256 + (n&31)*8 + (c&7).
__device__ __forceinline__ size_t swz(int n, int c) {
    return (size_t)(n >> 5) * 8192 + (size_t)((c >> 3) * 256) + (size_t)((n & 31) * 8) + (c & 7);
}

// ---------------- K1: fused preprocessing, 512 threads/block.
// grid: [0,864) patterns (1 voxel x 16 channels per thread, LDS max-merge);
//       [864,1376) codebook (2 rows/block) ; [1376,1808) z (8 rows/block)
__global__ __launch_bounds__(512) void k_pre(
        const float* __restrict__ in, const float* __restrict__ cb,
        const float* __restrict__ ze,
        unsigned long long* __restrict__ pats,
        float* __restrict__ scal,
        unsigned short* __restrict__ ehi, unsigned short* __restrict__ elo,
        unsigned short* __restrict__ zhi, unsigned short* __restrict__ zlo) {
    int bid = blockIdx.x;
    int t = threadIdx.x;
    __shared__ float mx1[256];
    __shared__ float ws[32];
    if (bid < 864) {
        // ---- patterns: 256 voxels/block; thread (v = t&255, h = t>>8)
        //      reduces channels [h*16, h*16+16).  4x the waves of the old
        //      1-thread-32-channel form (per-wave volume 16 KB -> 4 KB).
        if (bid == 0 && t < 16) scal[t] = 0.0f;   // scal[0..7] + done counter
        int vl = t & 255, h = t >> 8;
        int v = bid * 256 + vl;
        int b = v / VOX;
        int r = v % VOX;
        const float* p = in + ((size_t)b * NCH + h * 16) * VOX + r;
        float vals[16];
#pragma unroll
        for (int c = 0; c < 16; ++c) vals[c] = p[(size_t)c * VOX];
        if (h == 1) {
            float m = vals[0];
#pragma unroll
            for (int c = 1; c < 16; ++c) m = fmaxf(m, vals[c]);
            mx1[vl] = m;
        }
        __syncthreads();
        if (h == 0) {
            float v0 = vals[0];
            float m = vals[1];
#pragma unroll
            for (int c = 2; c < 16; ++c) m = fmaxf(m, vals[c]);
            m = fmaxf(m, mx1[vl]);
            unsigned long long bm = __ballot(m > v0);
            if ((t & 63) == 0) pats[v >> 6] = bm;
        }
        return;
    }
    int w = t >> 6, lane = t & 63;
    if (bid < 1376) {
        // ---- codebook: 2 rows/block; thread (c = t&255, h = t>>8) -> row k
        int h = t >> 8, c = t & 255;
        int k = (bid - 864) * 2 + h;
        float v = cb[k * C_DIM + c];
        float ss = v * v;
#pragma unroll
        for (int off = 32; off > 0; off >>= 1) ss += __shfl_down(ss, off, 64);
        if (lane == 0) ws[w] = ss;
        __syncthreads();
        float nrm = fmaxf(sqrtf(ws[h * 4 + 0] + ws[h * 4 + 1] + ws[h * 4 + 2] + ws[h * 4 + 3]), 1e-12f);
        float o = v / nrm;
        unsigned short hh = f2bf_rne(o);
        size_t off = swz(k, c);
        ehi[off] = hh;
        elo[off] = f2bf_rne(o - bf2f(hh));
    } else {
        // ---- z: 8 rows/block via float4 over s (216 % 8 == 0 -> same b)
        int zb = bid - 1376;             // 0..431
        int n0 = zb * 8;
        int b = n0 / SPATIAL, s0 = n0 - b * SPATIAL;
        int h = t >> 8, c = t & 255;     // h = row-quad 0/1
        float4 v4 = *(const float4*)&ze[((size_t)(b * C_DIM + c)) * SPATIAL + s0 + h * 4];
        float q0 = v4.x * v4.x, q1 = v4.y * v4.y, q2 = v4.z * v4.z, q3 = v4.w * v4.w;
#pragma unroll
        for (int off = 32; off > 0; off >>= 1) {
            q0 += __shfl_down(q0, off, 64);
            q1 += __shfl_down(q1, off, 64);
            q2 += __shfl_down(q2, off, 64);
            q3 += __shfl_down(q3, off, 64);
        }
        if (lane == 0) {
            int wi = w & 3;              // wave index within row-quad group
            ws[h * 16 + wi * 4 + 0] = q0;
            ws[h * 16 + wi * 4 + 1] = q1;
            ws[h * 16 + wi * 4 + 2] = q2;
            ws[h * 16 + wi * 4 + 3] = q3;
        }
        __syncthreads();
        float vv[4] = {v4.x, v4.y, v4.z, v4.w};
#pragma unroll
        for (int j = 0; j < 4; ++j) {
            float nrm = fmaxf(sqrtf(ws[h * 16 + j] + ws[h * 16 + 4 + j] +
                                    ws[h * 16 + 8 + j] + ws[h * 16 + 12 + j]), 1e-12f);
            float o = vv[j] / nrm;
            unsigned short hh = f2bf_rne(o);
            size_t off = swz(n0 + h * 4 + j, c);
            zhi[off] = hh;
            zlo[off] = f2bf_rne(o - bf2f(hh));
        }
    }
}

// ------------- K2: ONE fat kernel, 512 threads (8 waves) per block.
// Byte-level restore of the round-4 body (best measured: 51.2 us), with one
// change: the zq gather reconstructs en[mi] from ehi+elo (exact fp32 sum of
// the two bf16 halves, err <= 2^-17), removing the en buffer entirely.
// blocks [0,108): fused affinity GEMM + argmax + softmax stats + z_q.
// blocks [108,486): hamming Gram tiles, 8 waves = (i-strip, k-half).
// Last of all 486 blocks computes avg-entropy + final loss.
__global__ __launch_bounds__(512) void k_fat(
        const unsigned short* __restrict__ zhi, const unsigned short* __restrict__ zlo,
        const unsigned short* __restrict__ ehi, const unsigned short* __restrict__ elo,
        const unsigned long long* __restrict__ pats,
        float* __restrict__ avgp_part, float* __restrict__ scal,
        float* __restrict__ out) {
    __shared__ float zq[32 * 257];     // 32.9 KB transpose buffer
    __shared__ float sm[32][8];        // per-wave row max
    __shared__ int   si[32][8];        // per-wave row argmax
    __shared__ float sS[32][8];        // per-wave row sum(e)
    __shared__ float sT[32][8];        // per-wave row sum(e*d)
    __shared__ float gm[32];           // global row max
    __shared__ int   gmi[32];          // global row argmax
    __shared__ float invS[32];
    __shared__ float ws8[8];
    __shared__ float hw8[8], hd8[8];   // ham partials per wave
    __shared__ int lastflag;
    unsigned int* done = (unsigned int*)&scal[8];

    int t = threadIdx.x;
    int w = t >> 6, lane = t & 63;
    int half = lane >> 5, l31 = lane & 31;
    int bid = blockIdx.x;
    const bf16x8* __restrict__ Zh = (const bf16x8*)zhi;   // [strip][1024 chunks]
    const bf16x8* __restrict__ Zl = (const bf16x8*)zlo;
    const bf16x8* __restrict__ Eh = (const bf16x8*)ehi;
    const bf16x8* __restrict__ El = (const bf16x8*)elo;

    if (bid < N_GBLK) {
        // ===== fused GEMM + stats: rows [bid*32, bid*32+32) x cols [0,1024)
        int sa = bid;                  // A strip (32 rows)
        int n0 = bid * 32;

        f32x16 acc[4];
#pragma unroll
        for (int q = 0; q < 4; ++q)
#pragma unroll
            for (int e = 0; e < 16; ++e) acc[q][e] = 0.0f;

#pragma unroll
        for (int s16 = 0; s16 < 16; ++s16) {    // 16 k-steps of 16
            int u = s16 * 64 + lane;
            bf16x8 ah = Zh[(size_t)sa * 1024 + u];
            bf16x8 al = Zl[(size_t)sa * 1024 + u];
            bf16x8 bh[4], bl[4];
#pragma unroll
            for (int q = 0; q < 4; ++q) {
                bh[q] = Eh[(size_t)(w * 4 + q) * 1024 + u];
                bl[q] = El[(size_t)(w * 4 + q) * 1024 + u];
            }
#pragma unroll
            for (int q = 0; q < 4; ++q) {
                acc[q] = __builtin_amdgcn_mfma_f32_32x32x16_bf16(ah, bh[q], acc[q], 0, 0, 0);
                acc[q] = __builtin_amdgcn_mfma_f32_32x32x16_bf16(ah, bl[q], acc[q], 0, 0, 0);
                acc[q] = __builtin_amdgcn_mfma_f32_32x32x16_bf16(al, bh[q], acc[q], 0, 0, 0);
            }
        }
        // C/D layout (m74/m101): col = w*128 + q*32 + l31,
        //                        row = (g&3)+8*(g>>2)+4*half

        // --- P1: per-wave row max+argmax over this wave's 128-col slice
#pragma unroll
        for (int g = 0; g < 16; ++g) {
            float m = acc[0][g];
            int mi = w * 128 + l31;
#pragma unroll
            for (int q = 1; q < 4; ++q) {
                float x = acc[q][g];
                int c = w * 128 + q * 32 + l31;
                if (x > m) { m = x; mi = c; }
            }
#pragma unroll
            for (int mask = 1; mask < 32; mask <<= 1) {
                float vo = __shfl_xor(m, mask, 64);
                int   io = __shfl_xor(mi, mask, 64);
                if (vo > m || (vo == m && io < mi)) { m = vo; mi = io; }
            }
            int row = (g & 3) + 8 * (g >> 2) + 4 * half;
            if (l31 == 0) { sm[row][w] = m; si[row][w] = mi; }
        }
        __syncthreads();

        // --- P2: merge across waves -> global row max/idx; idx out; commit
        float cmv = 0.0f;
        if (t < 32) {
            float m = sm[t][0];
            int mi = si[t][0];
#pragma unroll
            for (int ww = 1; ww < 8; ++ww) {
                float mw = sm[t][ww];
                int miw = si[t][ww];
                if (mw > m || (mw == m && miw < mi)) { m = mw; mi = miw; }
            }
            gm[t] = m; gmi[t] = mi;
            out[884737 + n0 + t] = (float)mi;
            cmv = 2.0f - 2.0f * m;
        }
        if (w == 0) {
#pragma unroll
            for (int off = 32; off > 0; off >>= 1) cmv += __shfl_down(cmv, off, 64);
            if (lane == 0) atomicAdd(&scal[1], cmv);
        }
        __syncthreads();

        // --- P3: exp relative to global max; per-wave S,T partials; overwrite
        //         acc with e.  Gather en[argmax] rows into zq from ehi+elo.
#pragma unroll
        for (int g = 0; g < 16; ++g) {
            int row = (g & 3) + 8 * (g >> 2) + 4 * half;
            float gmr = gm[row];
            float S = 0.0f, T = 0.0f;
#pragma unroll
            for (int q = 0; q < 4; ++q) {
                float d = 100.0f * (acc[q][g] - gmr);
                float ee = __expf(d);
                S += ee; T += ee * d;
                acc[q][g] = ee;
            }
#pragma unroll
            for (int mask = 1; mask < 32; mask <<= 1) {
                S += __shfl_xor(S, mask, 64);
                T += __shfl_xor(T, mask, 64);
            }
            if (l31 == 0) { sS[row][w] = S; sT[row][w] = T; }
        }
#pragma unroll
        for (int rr = 0; rr < 4; ++rr) {
            int row = w * 4 + rr;
            int mi = gmi[row];
            size_t off = swz(mi, lane * 4);          // 4 consecutive c, one 8-group
            const ushort4 h4 = *(const ushort4*)&ehi[off];
            const ushort4 l4 = *(const ushort4*)&elo[off];
            zq[row * 257 + lane * 4 + 0] = bf2f(h4.x) + bf2f(l4.x);
            zq[row * 257 + lane * 4 + 1] = bf2f(h4.y) + bf2f(l4.y);
            zq[row * 257 + lane * 4 + 2] = bf2f(h4.z) + bf2f(l4.z);
            zq[row * 257 + lane * 4 + 3] = bf2f(h4.w) + bf2f(l4.w);
        }
        __syncthreads();

        // --- P4a: merge S,T across waves; sample-entropy contribution
        float sev = 0.0f;
        if (t < 32) {
            float S = 0.0f, T = 0.0f;
#pragma unroll
            for (int ww = 0; ww < 8; ++ww) { S += sS[t][ww]; T += sT[t][ww]; }
            float iv = 1.0f / S;
            invS[t] = iv;
            sev = logf(S) - T * iv;
        }
        if (w == 0) {
#pragma unroll
            for (int off = 32; off > 0; off >>= 1) sev += __shfl_down(sev, off, 64);
            if (lane == 0) atomicAdd(&scal[0], sev);
        }
        __syncthreads();

        // --- P4b: per-block avgp partial: col sums of probs over 32 rows
        {
            float cs[4] = {0.0f, 0.0f, 0.0f, 0.0f};
#pragma unroll
            for (int g = 0; g < 16; ++g) {
                int row = (g & 3) + 8 * (g >> 2) + 4 * half;
                float iv = invS[row];
#pragma unroll
                for (int q = 0; q < 4; ++q) cs[q] += acc[q][g] * iv;
            }
#pragma unroll
            for (int q = 0; q < 4; ++q) cs[q] += __shfl_xor(cs[q], 32, 64);
            if (half == 0) {
#pragma unroll
                for (int q = 0; q < 4; ++q)
                    avgp_part[(size_t)bid * K_CB + w * 128 + q * 32 + l31] = cs[q];
            }
        }

        // --- P5: z_q scatter from zq. thread t -> (row rl = t&31, cols cg*16..)
        {
            int rl = t & 31, cg = t >> 5;
            int n = n0 + rl;
            int b = n / SPATIAL, s = n - b * SPATIAL;
            size_t obase = ((size_t)b * C_DIM) * SPATIAL + s;
#pragma unroll
            for (int cc = 0; cc < 16; ++cc) {
                int c = cg * 16 + cc;
                out[obase + (size_t)c * SPATIAL] = zq[rl * 257 + c];
            }
        }
    } else {
        // ===== HAM branch: pairwise Gram, upper-tri 128x128 tiles.
        // 8 waves: wave w = (i-strip iw = w&3, k-half kh = w>>2).
        int hb = bid - N_GBLK;           // 0..377
        int ti = 0, rem = hb;
        while (rem >= 27 - ti) { rem -= 27 - ti; ++ti; }
        int tj = ti + rem;
        int i0 = ti * 128, j0 = tj * 128;
        float factor = (ti == tj) ? 1.0f : 2.0f;
        int iw = w & 3, kh = w >> 2;
        int sib = ti * 4 + iw;           // A strip for this wave (32 rows)
        int sjb = tj * 4;                // B strips (4)

        f32x16 acc[4];
#pragma unroll
        for (int c = 0; c < 4; ++c)
#pragma unroll
            for (int e = 0; e < 16; ++e) acc[c][e] = 0.0f;

#pragma unroll
        for (int s8 = 0; s8 < 8; ++s8) {     // this wave's k-half
            int u = (kh * 8 + s8) * 64 + lane;
            bf16x8 a0 = Zh[(size_t)sib * 1024 + u];
            bf16x8 bf[4];
#pragma unroll
            for (int c = 0; c < 4; ++c)
                bf[c] = Zh[(size_t)(sjb + c) * 1024 + u];
#pragma unroll
            for (int c = 0; c < 4; ++c)
                acc[c] = __builtin_amdgcn_mfma_f32_32x32x16_bf16(a0, bf[c], acc[c], 0, 0, 0);
        }

        unsigned long long pj[4];
#pragma unroll
        for (int c = 0; c < 4; ++c) pj[c] = pats[j0 + c * 32 + l31];

        float sW = 0.0f, sD = 0.0f;
        int ibase = i0 + iw * 32 + 4 * half;
#pragma unroll
        for (int g = 0; g < 16; ++g) {
            int gi = ibase + (g & 3) + 8 * (g >> 2);
            unsigned long long pi = pats[gi];
#pragma unroll
            for (int c = 0; c < 4; ++c) {
                int gj = j0 + c * 32 + l31;
                int pop = __popcll(pi ^ pj[c]);
                float wgt = (pop <= 5 && gi != gj) ? (1.0f - (float)pop * 0.015625f) : 0.0f;
                sW += wgt;
                sD += wgt * acc[c][g];
            }
        }
#pragma unroll
        for (int off = 32; off > 0; off >>= 1) {
            sW += __shfl_down(sW, off, 64);
            sD += __shfl_down(sD, off, 64);
        }
        if (lane == 0) { hw8[w] = sW; hd8[w] = sD; }
        __syncthreads();
        if (t == 0) {
            float W = hw8[0] + hw8[1] + hw8[2] + hw8[3];   // kh==0 only
            float D = hd8[0] + hd8[1] + hd8[2] + hd8[3]
                    + hd8[4] + hd8[5] + hd8[6] + hd8[7];
            atomicAdd(&scal[2], factor * W);
            atomicAdd(&scal[3], factor * D);
        }
    }

    // ===== common: done counter + last-block final loss
    __syncthreads();
    if (t == 0) {
        __threadfence();
        unsigned int old = atomicAdd(done, 1u);
        lastflag = (old == N_FBLK - 1) ? 1 : 0;
    }
    __syncthreads();
    if (lastflag) {
        __threadfence();
        int col0 = t, col1 = t + 512;
        float p0 = 0.0f, p1 = 0.0f, p2 = 0.0f, p3 = 0.0f;
        float q0 = 0.0f, q1 = 0.0f, q2 = 0.0f, q3 = 0.0f;
        for (int bb = 0; bb < N_GBLK; bb += 4) {   // 8 independent load streams
            p0 += avgp_part[(size_t)(bb + 0) * K_CB + col0];
            p1 += avgp_part[(size_t)(bb + 1) * K_CB + col0];
            p2 += avgp_part[(size_t)(bb + 2) * K_CB + col0];
            p3 += avgp_part[(size_t)(bb + 3) * K_CB + col0];
            q0 += avgp_part[(size_t)(bb + 0) * K_CB + col1];
            q1 += avgp_part[(size_t)(bb + 1) * K_CB + col1];
            q2 += avgp_part[(size_t)(bb + 2) * K_CB + col1];
            q3 += avgp_part[(size_t)(bb + 3) * K_CB + col1];
        }
        float ap0 = (p0 + p1 + p2 + p3) * (1.0f / N_ROWS);
        float ap1 = (q0 + q1 + q2 + q3) * (1.0f / N_ROWS);
        float term = ap0 * logf(ap0 + 1e-5f) + ap1 * logf(ap1 + 1e-5f);
#pragma unroll
        for (int off = 32; off > 0; off >>= 1) term += __shfl_down(term, off, 64);
        if (lane == 0) ws8[w] = term;
        __syncthreads();
        if (t == 0) {
            float sAP = 0.0f;
#pragma unroll
            for (int i = 0; i < 8; ++i) sAP += ws8[i];
            float s0 = atomicAdd(&scal[0], 0.0f);
            float s1 = atomicAdd(&scal[1], 0.0f);
            float s2 = atomicAdd(&scal[2], 0.0f);
            float s3 = atomicAdd(&scal[3], 0.0f);
            float sample = s0 * (1.0f / N_ROWS);
            float commit = s1 * (1.0f / ((float)N_ROWS * C_DIM));
            float ent = 0.1f * (sample + sAP);
            float ham = (s2 - s3) / (s2 + 1e-8f);
            out[884736] = 1.25f * commit + ent + ham;
        }
    }
}

// ----------------------------------------------------------------- launch
extern "C" void kernel_launch(void* const* d_in, const int* in_sizes, int n_in,
                              void* d_out, int out_size, void* d_ws, size_t ws_size,
                              hipStream_t stream) {
    const float* in_blocks = (const float*)d_in[0];  // [16,32,24,24,24]
    const float* z_e       = (const float*)d_in[1];  // [16,256,6,6,6]
    const float* cb        = (const float*)d_in[2];  // [1024,256]
    float* out = (float*)d_out;  // [884736 z_q][1 loss][3456 idx]

    char* ws = (char*)d_ws;
    unsigned short* zhi = (unsigned short*)(ws + 15204352);  // 1,769,472 B (swizzled)
    unsigned short* zlo = (unsigned short*)(ws + 16973824);  // 1,769,472 B (swizzled)
    unsigned short* ehi = (unsigned short*)(ws + 18743296);  //   524,288 B (swizzled)
    unsigned short* elo = (unsigned short*)(ws + 19267584);  //   524,288 B (swizzled)
    unsigned long long* pats = (unsigned long long*)(ws + 19791872); // 27,648 B
    float* avgp_part = (float*)(ws + 19819520);      // 108*4096 = 442,368 B
    float* scal = (float*)(ws + 20704256);           // 64 B (scal[0..7] + done)

    k_pre<<<1808, 512, 0, stream>>>(in_blocks, cb, z_e, pats, scal,
                                    ehi, elo, zhi, zlo);
    k_fat<<<N_FBLK, 512, 0, stream>>>(zhi, zlo, ehi, elo, pats,
                                      avgp_part, scal, out);
}

// Round 11
// 127.563 us; speedup vs baseline: 1.2055x; 1.0127x over previous
//
#include <hip/hip_runtime.h>
#include <cstdint>
#include <cstddef>

#define N_ROWS 3456   // 16*216 chunks
#define C_DIM 256
#define K_CB 1024
#define B_SZ 16
#define SPATIAL 216
#define VOX 13824     // 24*24*24
#define NCH 32
#define N_GBLK 108    // fused gemm+stat blocks (32 rows x 1024 cols each)
#define N_FBLK 486    // 108 gemm + 378 ham

typedef __attribute__((ext_vector_type(16))) float f32x16;
typedef __attribute__((ext_vector_type(8))) short bf16x8;

__device__ __forceinline__ unsigned short f2bf_rne(float f) {
    unsigned int u = __float_as_uint(f);
    u += 0x7FFFu + ((u >> 16) & 1u);
    return (unsigned short)(u >> 16);
}
__device__ __forceinline__ float bf2f(unsigned short h) {
    unsigned int u = ((unsigned int)h) << 16;
    return __uint_as_float(u);
}

// Swizzled fragment layout: element (row n, col c) of a [rows x 256] matrix
// lives at  strip(n>>5)*8192 + (c>>3)*256 + (n&31)*8 + (c&7).
__device__ __forceinline__ size_t swz(int n, int c) {
    return (size_t)(n >> 5) * 8192 + (size_t)((c >> 3) * 256) + (size_t)((n & 31) * 8) + (c & 7);
}

// ---------------- K1: fused preprocessing, 512 threads/block (R10 form,
// measured ~12 us; cb branch additionally writes the fp32 en buffer back).
// grid: [0,864) patterns (1 voxel x 16 channels per thread, LDS max-merge);
//       [864,1376) codebook (2 rows/block) ; [1376,1808) z (8 rows/block)
__global__ __launch_bounds__(512) void k_pre(
        const float* __restrict__ in, const float* __restrict__ cb,
        const float* __restrict__ ze,
        unsigned long long* __restrict__ pats,
        float* __restrict__ scal,
        float* __restrict__ en,
        unsigned short* __restrict__ ehi, unsigned short* __restrict__ elo,
        unsigned short* __restrict__ zhi, unsigned short* __restrict__ zlo) {
    int bid = blockIdx.x;
    int t = threadIdx.x;
    __shared__ float mx1[256];
    __shared__ float ws[32];
    if (bid < 864) {
        // ---- patterns: 256 voxels/block; thread (v = t&255, h = t>>8)
        //      reduces channels [h*16, h*16+16).
        if (bid == 0 && t < 16) scal[t] = 0.0f;   // scal[0..7] + done counter
        int vl = t & 255, h = t >> 8;
        int v = bid * 256 + vl;
        int b = v / VOX;
        int r = v % VOX;
        const float* p = in + ((size_t)b * NCH + h * 16) * VOX + r;
        float vals[16];
#pragma unroll
        for (int c = 0; c < 16; ++c) vals[c] = p[(size_t)c * VOX];
        if (h == 1) {
            float m = vals[0];
#pragma unroll
            for (int c = 1; c < 16; ++c) m = fmaxf(m, vals[c]);
            mx1[vl] = m;
        }
        __syncthreads();
        if (h == 0) {
            float v0 = vals[0];
            float m = vals[1];
#pragma unroll
            for (int c = 2; c < 16; ++c) m = fmaxf(m, vals[c]);
            m = fmaxf(m, mx1[vl]);
            unsigned long long bm = __ballot(m > v0);
            if ((t & 63) == 0) pats[v >> 6] = bm;
        }
        return;
    }
    int w = t >> 6, lane = t & 63;
    if (bid < 1376) {
        // ---- codebook: 2 rows/block; thread (c = t&255, h = t>>8) -> row k
        int h = t >> 8, c = t & 255;
        int k = (bid - 864) * 2 + h;
        float v = cb[k * C_DIM + c];
        float ss = v * v;
#pragma unroll
        for (int off = 32; off > 0; off >>= 1) ss += __shfl_down(ss, off, 64);
        if (lane == 0) ws[w] = ss;
        __syncthreads();
        float nrm = fmaxf(sqrtf(ws[h * 4 + 0] + ws[h * 4 + 1] + ws[h * 4 + 2] + ws[h * 4 + 3]), 1e-12f);
        float o = v / nrm;
        en[k * C_DIM + c] = o;
        unsigned short hh = f2bf_rne(o);
        size_t off = swz(k, c);
        ehi[off] = hh;
        elo[off] = f2bf_rne(o - bf2f(hh));
    } else {
        // ---- z: 8 rows/block via float4 over s (216 % 8 == 0 -> same b)
        int zb = bid - 1376;             // 0..431
        int n0 = zb * 8;
        int b = n0 / SPATIAL, s0 = n0 - b * SPATIAL;
        int h = t >> 8, c = t & 255;     // h = row-quad 0/1
        float4 v4 = *(const float4*)&ze[((size_t)(b * C_DIM + c)) * SPATIAL + s0 + h * 4];
        float q0 = v4.x * v4.x, q1 = v4.y * v4.y, q2 = v4.z * v4.z, q3 = v4.w * v4.w;
#pragma unroll
        for (int off = 32; off > 0; off >>= 1) {
            q0 += __shfl_down(q0, off, 64);
            q1 += __shfl_down(q1, off, 64);
            q2 += __shfl_down(q2, off, 64);
            q3 += __shfl_down(q3, off, 64);
        }
        if (lane == 0) {
            int wi = w & 3;              // wave index within row-quad group
            ws[h * 16 + wi * 4 + 0] = q0;
            ws[h * 16 + wi * 4 + 1] = q1;
            ws[h * 16 + wi * 4 + 2] = q2;
            ws[h * 16 + wi * 4 + 3] = q3;
        }
        __syncthreads();
        float vv[4] = {v4.x, v4.y, v4.z, v4.w};
#pragma unroll
        for (int j = 0; j < 4; ++j) {
            float nrm = fmaxf(sqrtf(ws[h * 16 + j] + ws[h * 16 + 4 + j] +
                                    ws[h * 16 + 8 + j] + ws[h * 16 + 12 + j]), 1e-12f);
            float o = vv[j] / nrm;
            unsigned short hh = f2bf_rne(o);
            size_t off = swz(n0 + h * 4 + j, c);
            zhi[off] = hh;
            zlo[off] = f2bf_rne(o - bf2f(hh));
        }
    }
}

// ------------- K2: ONE fat kernel, 512 threads (8 waves) per block.
// Byte-exact round-4 body (best measured: 51.2 us), en buffer + fp32
// float4 gather restored (the R10 swz-scattered gather regressed 22 us).
// blocks [0,108): fused affinity GEMM + argmax + softmax stats + z_q.
// blocks [108,486): hamming Gram tiles, 8 waves = (i-strip, k-half).
// Last of all 486 blocks computes avg-entropy + final loss.
__global__ __launch_bounds__(512) void k_fat(
        const unsigned short* __restrict__ zhi, const unsigned short* __restrict__ zlo,
        const unsigned short* __restrict__ ehi, const unsigned short* __restrict__ elo,
        const unsigned long long* __restrict__ pats,
        const float* __restrict__ en,
        float* __restrict__ avgp_part, float* __restrict__ scal,
        float* __restrict__ out) {
    __shared__ float zq[32 * 257];     // 32.9 KB transpose buffer
    __shared__ float sm[32][8];        // per-wave row max
    __shared__ int   si[32][8];        // per-wave row argmax
    __shared__ float sS[32][8];        // per-wave row sum(e)
    __shared__ float sT[32][8];        // per-wave row sum(e*d)
    __shared__ float gm[32];           // global row max
    __shared__ int   gmi[32];          // global row argmax
    __shared__ float invS[32];
    __shared__ float ws8[8];
    __shared__ float hw8[8], hd8[8];   // ham partials per wave
    __shared__ int lastflag;
    unsigned int* done = (unsigned int*)&scal[8];

    int t = threadIdx.x;
    int w = t >> 6, lane = t & 63;
    int half = lane >> 5, l31 = lane & 31;
    int bid = blockIdx.x;
    const bf16x8* __restrict__ Zh = (const bf16x8*)zhi;   // [strip][1024 chunks]
    const bf16x8* __restrict__ Zl = (const bf16x8*)zlo;
    const bf16x8* __restrict__ Eh = (const bf16x8*)ehi;
    const bf16x8* __restrict__ El = (const bf16x8*)elo;

    if (bid < N_GBLK) {
        // ===== fused GEMM + stats: rows [bid*32, bid*32+32) x cols [0,1024)
        int sa = bid;                  // A strip (32 rows)
        int n0 = bid * 32;

        f32x16 acc[4];
#pragma unroll
        for (int q = 0; q < 4; ++q)
#pragma unroll
            for (int e = 0; e < 16; ++e) acc[q][e] = 0.0f;

#pragma unroll
        for (int s16 = 0; s16 < 16; ++s16) {    // 16 k-steps of 16
            int u = s16 * 64 + lane;
            bf16x8 ah = Zh[(size_t)sa * 1024 + u];
            bf16x8 al = Zl[(size_t)sa * 1024 + u];
            bf16x8 bh[4], bl[4];
#pragma unroll
            for (int q = 0; q < 4; ++q) {
                bh[q] = Eh[(size_t)(w * 4 + q) * 1024 + u];
                bl[q] = El[(size_t)(w * 4 + q) * 1024 + u];
            }
#pragma unroll
            for (int q = 0; q < 4; ++q) {
                acc[q] = __builtin_amdgcn_mfma_f32_32x32x16_bf16(ah, bh[q], acc[q], 0, 0, 0);
                acc[q] = __builtin_amdgcn_mfma_f32_32x32x16_bf16(ah, bl[q], acc[q], 0, 0, 0);
                acc[q] = __builtin_amdgcn_mfma_f32_32x32x16_bf16(al, bh[q], acc[q], 0, 0, 0);
            }
        }
        // C/D layout (m74/m101): col = w*128 + q*32 + l31,
        //                        row = (g&3)+8*(g>>2)+4*half

        // --- P1: per-wave row max+argmax over this wave's 128-col slice
#pragma unroll
        for (int g = 0; g < 16; ++g) {
            float m = acc[0][g];
            int mi = w * 128 + l31;
#pragma unroll
            for (int q = 1; q < 4; ++q) {
                float x = acc[q][g];
                int c = w * 128 + q * 32 + l31;
                if (x > m) { m = x; mi = c; }
            }
#pragma unroll
            for (int mask = 1; mask < 32; mask <<= 1) {
                float vo = __shfl_xor(m, mask, 64);
                int   io = __shfl_xor(mi, mask, 64);
                if (vo > m || (vo == m && io < mi)) { m = vo; mi = io; }
            }
            int row = (g & 3) + 8 * (g >> 2) + 4 * half;
            if (l31 == 0) { sm[row][w] = m; si[row][w] = mi; }
        }
        __syncthreads();

        // --- P2: merge across waves -> global row max/idx; idx out; commit
        float cmv = 0.0f;
        if (t < 32) {
            float m = sm[t][0];
            int mi = si[t][0];
#pragma unroll
            for (int ww = 1; ww < 8; ++ww) {
                float mw = sm[t][ww];
                int miw = si[t][ww];
                if (mw > m || (mw == m && miw < mi)) { m = mw; mi = miw; }
            }
            gm[t] = m; gmi[t] = mi;
            out[884737 + n0 + t] = (float)mi;
            cmv = 2.0f - 2.0f * m;
        }
        if (w == 0) {
#pragma unroll
            for (int off = 32; off > 0; off >>= 1) cmv += __shfl_down(cmv, off, 64);
            if (lane == 0) atomicAdd(&scal[1], cmv);
        }
        __syncthreads();

        // --- P3: exp relative to global max; per-wave S,T partials; overwrite
        //         acc with e.  Also gather en[argmax] rows into zq.
#pragma unroll
        for (int g = 0; g < 16; ++g) {
            int row = (g & 3) + 8 * (g >> 2) + 4 * half;
            float gmr = gm[row];
            float S = 0.0f, T = 0.0f;
#pragma unroll
            for (int q = 0; q < 4; ++q) {
                float d = 100.0f * (acc[q][g] - gmr);
                float ee = __expf(d);
                S += ee; T += ee * d;
                acc[q][g] = ee;
            }
#pragma unroll
            for (int mask = 1; mask < 32; mask <<= 1) {
                S += __shfl_xor(S, mask, 64);
                T += __shfl_xor(T, mask, 64);
            }
            if (l31 == 0) { sS[row][w] = S; sT[row][w] = T; }
        }
#pragma unroll
        for (int rr = 0; rr < 4; ++rr) {
            int row = w * 4 + rr;
            int mi = gmi[row];
            float4 g4 = *(const float4*)&en[(size_t)mi * C_DIM + lane * 4];
            zq[row * 257 + lane * 4 + 0] = g4.x;
            zq[row * 257 + lane * 4 + 1] = g4.y;
            zq[row * 257 + lane * 4 + 2] = g4.z;
            zq[row * 257 + lane * 4 + 3] = g4.w;
        }
        __syncthreads();

        // --- P4a: merge S,T across waves; sample-entropy contribution
        float sev = 0.0f;
        if (t < 32) {
            float S = 0.0f, T = 0.0f;
#pragma unroll
            for (int ww = 0; ww < 8; ++ww) { S += sS[t][ww]; T += sT[t][ww]; }
            float iv = 1.0f / S;
            invS[t] = iv;
            sev = logf(S) - T * iv;
        }
        if (w == 0) {
#pragma unroll
            for (int off = 32; off > 0; off >>= 1) sev += __shfl_down(sev, off, 64);
            if (lane == 0) atomicAdd(&scal[0], sev);
        }
        __syncthreads();

        // --- P4b: per-block avgp partial: col sums of probs over 32 rows
        {
            float cs[4] = {0.0f, 0.0f, 0.0f, 0.0f};
#pragma unroll
            for (int g = 0; g < 16; ++g) {
                int row = (g & 3) + 8 * (g >> 2) + 4 * half;
                float iv = invS[row];
#pragma unroll
                for (int q = 0; q < 4; ++q) cs[q] += acc[q][g] * iv;
            }
#pragma unroll
            for (int q = 0; q < 4; ++q) cs[q] += __shfl_xor(cs[q], 32, 64);
            if (half == 0) {
#pragma unroll
                for (int q = 0; q < 4; ++q)
                    avgp_part[(size_t)bid * K_CB + w * 128 + q * 32 + l31] = cs[q];
            }
        }

        // --- P5: z_q scatter from zq. thread t -> (row rl = t&31, cols cg*16..)
        {
            int rl = t & 31, cg = t >> 5;
            int n = n0 + rl;
            int b = n / SPATIAL, s = n - b * SPATIAL;
            size_t obase = ((size_t)b * C_DIM) * SPATIAL + s;
#pragma unroll
            for (int cc = 0; cc < 16; ++cc) {
                int c = cg * 16 + cc;
                out[obase + (size_t)c * SPATIAL] = zq[rl * 257 + c];
            }
        }
    } else {
        // ===== HAM branch: pairwise Gram, upper-tri 128x128 tiles.
        // 8 waves: wave w = (i-strip iw = w&3, k-half kh = w>>2).
        int hb = bid - N_GBLK;           // 0..377
        int ti = 0, rem = hb;
        while (rem >= 27 - ti) { rem -= 27 - ti; ++ti; }
        int tj = ti + rem;
        int i0 = ti * 128, j0 = tj * 128;
        float factor = (ti == tj) ? 1.0f : 2.0f;
        int iw = w & 3, kh = w >> 2;
        int sib = ti * 4 + iw;           // A strip for this wave (32 rows)
        int sjb = tj * 4;                // B strips (4)

        f32x16 acc[4];
#pragma unroll
        for (int c = 0; c < 4; ++c)
#pragma unroll
            for (int e = 0; e < 16; ++e) acc[c][e] = 0.0f;

#pragma unroll
        for (int s8 = 0; s8 < 8; ++s8) {     // this wave's k-half
            int u = (kh * 8 + s8) * 64 + lane;
            bf16x8 a0 = Zh[(size_t)sib * 1024 + u];
            bf16x8 bf[4];
#pragma unroll
            for (int c = 0; c < 4; ++c)
                bf[c] = Zh[(size_t)(sjb + c) * 1024 + u];
#pragma unroll
            for (int c = 0; c < 4; ++c)
                acc[c] = __builtin_amdgcn_mfma_f32_32x32x16_bf16(a0, bf[c], acc[c], 0, 0, 0);
        }

        unsigned long long pj[4];
#pragma unroll
        for (int c = 0; c < 4; ++c) pj[c] = pats[j0 + c * 32 + l31];

        float sW = 0.0f, sD = 0.0f;
        int ibase = i0 + iw * 32 + 4 * half;
#pragma unroll
        for (int g = 0; g < 16; ++g) {
            int gi = ibase + (g & 3) + 8 * (g >> 2);
            unsigned long long pi = pats[gi];
#pragma unroll
            for (int c = 0; c < 4; ++c) {
                int gj = j0 + c * 32 + l31;
                int pop = __popcll(pi ^ pj[c]);
                float wgt = (pop <= 5 && gi != gj) ? (1.0f - (float)pop * 0.015625f) : 0.0f;
                sW += wgt;
                sD += wgt * acc[c][g];
            }
        }
#pragma unroll
        for (int off = 32; off > 0; off >>= 1) {
            sW += __shfl_down(sW, off, 64);
            sD += __shfl_down(sD, off, 64);
        }
        if (lane == 0) { hw8[w] = sW; hd8[w] = sD; }
        __syncthreads();
        if (t == 0) {
            float W = hw8[0] + hw8[1] + hw8[2] + hw8[3];   // kh==0 only
            float D = hd8[0] + hd8[1] + hd8[2] + hd8[3]
                    + hd8[4] + hd8[5] + hd8[6] + hd8[7];
            atomicAdd(&scal[2], factor * W);
            atomicAdd(&scal[3], factor * D);
        }
    }

    // ===== common: done counter + last-block final loss
    __syncthreads();
    if (t == 0) {
        __threadfence();
        unsigned int old = atomicAdd(done, 1u);
        lastflag = (old == N_FBLK - 1) ? 1 : 0;
    }
    __syncthreads();
    if (lastflag) {
        __threadfence();
        int col0 = t, col1 = t + 512;
        float p0 = 0.0f, p1 = 0.0f, p2 = 0.0f, p3 = 0.0f;
        float q0 = 0.0f, q1 = 0.0f, q2 = 0.0f, q3 = 0.0f;
        for (int bb = 0; bb < N_GBLK; bb += 4) {   // 8 independent load streams
            p0 += avgp_part[(size_t)(bb + 0) * K_CB + col0];
            p1 += avgp_part[(size_t)(bb + 1) * K_CB + col0];
            p2 += avgp_part[(size_t)(bb + 2) * K_CB + col0];
            p3 += avgp_part[(size_t)(bb + 3) * K_CB + col0];
            q0 += avgp_part[(size_t)(bb + 0) * K_CB + col1];
            q1 += avgp_part[(size_t)(bb + 1) * K_CB + col1];
            q2 += avgp_part[(size_t)(bb + 2) * K_CB + col1];
            q3 += avgp_part[(size_t)(bb + 3) * K_CB + col1];
        }
        float ap0 = (p0 + p1 + p2 + p3) * (1.0f / N_ROWS);
        float ap1 = (q0 + q1 + q2 + q3) * (1.0f / N_ROWS);
        float term = ap0 * logf(ap0 + 1e-5f) + ap1 * logf(ap1 + 1e-5f);
#pragma unroll
        for (int off = 32; off > 0; off >>= 1) term += __shfl_down(term, off, 64);
        if (lane == 0) ws8[w] = term;
        __syncthreads();
        if (t == 0) {
            float sAP = 0.0f;
#pragma unroll
            for (int i = 0; i < 8; ++i) sAP += ws8[i];
            float s0 = atomicAdd(&scal[0], 0.0f);
            float s1 = atomicAdd(&scal[1], 0.0f);
            float s2 = atomicAdd(&scal[2], 0.0f);
            float s3 = atomicAdd(&scal[3], 0.0f);
            float sample = s0 * (1.0f / N_ROWS);
            float commit = s1 * (1.0f / ((float)N_ROWS * C_DIM));
            float ent = 0.1f * (sample + sAP);
            float ham = (s2 - s3) / (s2 + 1e-8f);
            out[884736] = 1.25f * commit + ent + ham;
        }
    }
}

// ----------------------------------------------------------------- launch
extern "C" void kernel_launch(void* const* d_in, const int* in_sizes, int n_in,
                              void* d_out, int out_size, void* d_ws, size_t ws_size,
                              hipStream_t stream) {
    const float* in_blocks = (const float*)d_in[0];  // [16,32,24,24,24]
    const float* z_e       = (const float*)d_in[1];  // [16,256,6,6,6]
    const float* cb        = (const float*)d_in[2];  // [1024,256]
    float* out = (float*)d_out;  // [884736 z_q][1 loss][3456 idx]

    char* ws = (char*)d_ws;
    float* en   = (float*)(ws + 0);                  //  1,048,576 B
    unsigned short* zhi = (unsigned short*)(ws + 15204352);  // 1,769,472 B (swizzled)
    unsigned short* zlo = (unsigned short*)(ws + 16973824);  // 1,769,472 B (swizzled)
    unsigned short* ehi = (unsigned short*)(ws + 18743296);  //   524,288 B (swizzled)
    unsigned short* elo = (unsigned short*)(ws + 19267584);  //   524,288 B (swizzled)
    unsigned long long* pats = (unsigned long long*)(ws + 19791872); // 27,648 B
    float* avgp_part = (float*)(ws + 19819520);      // 108*4096 = 442,368 B
    float* scal = (float*)(ws + 20704256);           // 64 B (scal[0..7] + done)

    k_pre<<<1808, 512, 0, stream>>>(in_blocks, cb, z_e, pats, scal, en,
                                    ehi, elo, zhi, zlo);
    k_fat<<<N_FBLK, 512, 0, stream>>>(zhi, zlo, ehi, elo, pats, en,
                                      avgp_part, scal, out);
}